// Round 13
// baseline (294.052 us; speedup 1.0000x reference)
//
#include <hip/hip_runtime.h>
#include <hip/hip_bf16.h>

#define N_NODES 50000
#define N_EDGES 800000
#define IN_DIM  128
#define H_DIM   96
#define C_DIM   10
#define L_LAYERS 4
#define K_EIG   16
#define LN_EPS_F 1e-5f

// edge-partition geometry (round-8 proven build, packed 4B payload)
#define EPB 4096                 // edges per partition block
#define NPB 196                  // ceil(N_EDGES / EPB)
#define BKT 512                  // dst nodes per bucket
#define NBK 98                   // ceil(N_NODES / BKT)

typedef __attribute__((ext_vector_type(8))) short bf16x8;
typedef __attribute__((ext_vector_type(4))) float f32x4;

// ---------- device helpers ----------

__device__ __forceinline__ float gelu_f(float x) {
    return 0.5f * x * (1.0f + erff(x * 0.7071067811865476f));
}

__device__ __forceinline__ ushort f2bf(float f) {
    union { float f; unsigned int u; } v; v.f = f;
    unsigned int r = v.u + 0x7fffu + ((v.u >> 16) & 1u);
    return (ushort)(r >> 16);
}

__device__ __forceinline__ float bflo(unsigned int v) { return __uint_as_float(v << 16); }
__device__ __forceinline__ float bfhi(unsigned int v) { return __uint_as_float(v & 0xffff0000u); }
__device__ __forceinline__ float bf2f(ushort u) { return __uint_as_float(((unsigned)u) << 16); }

// ---------- graph preprocessing: bucketed CSR build ----------

__global__ void k_binA(const int* __restrict__ dst, int* __restrict__ cntmat) {
    __shared__ int hist[NBK];
    for (int i = threadIdx.x; i < NBK; i += 256) hist[i] = 0;
    __syncthreads();
    const int e0 = blockIdx.x * EPB;
    for (int i = threadIdx.x; i < EPB; i += 256) {
        int e = e0 + i;
        if (e < N_EDGES) atomicAdd(&hist[dst[e] >> 9], 1);
    }
    __syncthreads();
    for (int i = threadIdx.x; i < NBK; i += 256)
        cntmat[i * NPB + blockIdx.x] = hist[i];
}

__global__ void k_binB(int* __restrict__ cm, int n) {
    __shared__ int wsum[16];
    const int tid = threadIdx.x, lane = tid & 63, wid = tid >> 6;
    int carry = 0;
    for (int base = 0; base < n; base += 1024) {
        int i = base + tid;
        int v = (i < n) ? cm[i] : 0;
        int s = v;
#pragma unroll
        for (int off = 1; off < 64; off <<= 1) {
            int x = __shfl_up(s, off);
            if (lane >= off) s += x;
        }
        if (lane == 63) wsum[wid] = s;
        __syncthreads();
        if (tid < 64) {
            int ws = (lane < 16) ? wsum[lane] : 0;
#pragma unroll
            for (int off = 1; off < 16; off <<= 1) {
                int x = __shfl_up(ws, off);
                if (lane >= off) ws += x;
            }
            if (lane < 16) wsum[lane] = ws;
        }
        __syncthreads();
        int woff = (wid > 0) ? wsum[wid - 1] : 0;
        if (i < n) cm[i] = carry + woff + s - v;
        int tot = wsum[15];
        __syncthreads();
        carry += tot;
    }
    if (tid == 0) cm[n] = carry;
}

// C: partition edges into bucket-grouped packed array eb[] ((dstLocal<<16)|src)
__global__ void k_binC(const int* __restrict__ src, const int* __restrict__ dst,
                       const int* __restrict__ offs, unsigned int* __restrict__ eb) {
    __shared__ int cur[NBK];
    for (int i = threadIdx.x; i < NBK; i += 256) cur[i] = offs[i * NPB + blockIdx.x];
    __syncthreads();
    const int e0 = blockIdx.x * EPB;
    for (int i = threadIdx.x; i < EPB; i += 256) {
        int e = e0 + i;
        if (e < N_EDGES) {
            int d = dst[e];
            int slot = atomicAdd(&cur[d >> 9], 1);
            eb[slot] = ((unsigned)(d & (BKT - 1)) << 16) | (unsigned)src[e];
        }
    }
}

// D: per-bucket fine CSR fill + rowst + dinv
__global__ void k_binD(const unsigned int* __restrict__ eb, const int* __restrict__ offs,
                       int* __restrict__ rowst, float* __restrict__ dinv,
                       int* __restrict__ csr) {
    __shared__ int cnt[BKT];
    __shared__ int wsum[16];
    const int b = blockIdx.x, t = threadIdx.x;
    const int ebeg = offs[b * NPB], eend = offs[(b + 1) * NPB];
    for (int i = t; i < BKT; i += 1024) cnt[i] = 0;
    __syncthreads();
    for (int i = ebeg + t; i < eend; i += 1024)
        atomicAdd(&cnt[eb[i] >> 16], 1);
    __syncthreads();
    const int lane = t & 63, wid = t >> 6;
    int v = 0, s = 0;
    if (t < BKT) {
        v = cnt[t]; s = v;
#pragma unroll
        for (int off = 1; off < 64; off <<= 1) {
            int x = __shfl_up(s, off);
            if (lane >= off) s += x;
        }
        if (lane == 63) wsum[wid] = s;
    }
    __syncthreads();
    if (t < 64) {
        int ws = (lane < 8) ? wsum[lane] : 0;
#pragma unroll
        for (int off = 1; off < 8; off <<= 1) {
            int x = __shfl_up(ws, off);
            if (lane >= off) ws += x;
        }
        if (lane < 8) wsum[lane] = ws;
    }
    __syncthreads();
    if (t < BKT) {
        int woff = (wid > 0) ? wsum[wid - 1] : 0;
        int excl = ebeg + woff + s - v;
        int row = b * BKT + t;
        if (row < N_NODES) {
            rowst[row] = excl;
            dinv[row] = rsqrtf((float)v + 1.0f);
        }
        cnt[t] = excl;
    }
    __syncthreads();
    for (int i = ebeg + t; i < eend; i += 1024) {
        unsigned e = eb[i];
        int p = atomicAdd(&cnt[e >> 16], 1);
        csr[p] = (int)(e & 0xFFFFu);
    }
    if (b == 0 && t == 0) rowst[N_NODES] = N_EDGES;
}

// ---------- weight prep: transpose + bf16 ----------

struct WSrc { const float* p[10]; };

__global__ void k_prep(WSrc ws, ushort* __restrict__ out) {
    int idx = blockIdx.x * 256 + threadIdx.x;
    if (idx < 12288) {
        int n = idx >> 7, k = idx & 127;
        out[idx] = f2bf(ws.p[0][k * 96 + n]);
    } else if (idx < 12288 + 8 * 9216) {
        int j = idx - 12288;
        int m = j / 9216, r = j - m * 9216;
        int n = r / 96, k = r - n * 96;
        out[idx] = f2bf(ws.p[m + 1][k * 96 + n]);
    } else if (idx < 12288 + 8 * 9216 + 1536) {
        int j = idx - 12288 - 8 * 9216;
        int c = j / 96, k = j - c * 96;
        out[idx] = (c < C_DIM) ? f2bf(ws.p[9][k * C_DIM + c]) : (ushort)0;
    }
}

// ---------- MFMA GEMM, wave-per-16-rows, operands via registers ----------
// EPI 0: (.*dinv[row]) -> bf16 out         (conv xw', norm folded)
// EPI 2: LN(.+bias; g,beta) -> bf16 out    (encoder -> hb)
// EPI 5: head: t = LN(gelu(.+bias); g,beta); out = t @ W2 + b2 via 2nd MFMA
//   D mapping (HW-verified): row=(lane>>4)*4+reg, col=lane&15

template <int K_DIM, typename XT, int EPI>
__launch_bounds__(256)
__global__ void k_gemm(const XT* __restrict__ X, const ushort* __restrict__ Wt,
                       const float* __restrict__ bias, const float* __restrict__ g,
                       const float* __restrict__ beta, const float* __restrict__ dinvp,
                       const ushort* __restrict__ w2t, const float* __restrict__ b2,
                       void* __restrict__ outv) {
    constexpr int NK = K_DIM / 32;
    __shared__ ushort Tt[(EPI == 5) ? 4 * 16 * 104 : 4];
    const int lane = threadIdx.x & 63, wv = threadIdx.x >> 6;
    const int lrow = lane & 15, lk = (lane >> 4) * 8;
    const int grp = blockIdx.x * 4 + wv;
    if (grp >= N_NODES / 16) return;

    bf16x8 wf[6][NK];
#pragma unroll
    for (int nn = 0; nn < 6; ++nn)
#pragma unroll
        for (int kk = 0; kk < NK; ++kk)
            wf[nn][kk] = *(const bf16x8*)(&Wt[(size_t)(nn * 16 + lrow) * K_DIM + kk * 32 + lk]);

    bf16x8 af[NK];
    const int arow = grp * 16 + lrow;
    if constexpr (sizeof(XT) == 4) {
#pragma unroll
        for (int kk = 0; kk < NK; ++kk) {
            const float4* p = (const float4*)((const float*)X + (size_t)arow * K_DIM + kk * 32 + lk);
            float4 a = p[0], b = p[1];
            union { bf16x8 v; unsigned u[4]; } pk;
            pk.u[0] = (unsigned)f2bf(a.x) | ((unsigned)f2bf(a.y) << 16);
            pk.u[1] = (unsigned)f2bf(a.z) | ((unsigned)f2bf(a.w) << 16);
            pk.u[2] = (unsigned)f2bf(b.x) | ((unsigned)f2bf(b.y) << 16);
            pk.u[3] = (unsigned)f2bf(b.z) | ((unsigned)f2bf(b.w) << 16);
            af[kk] = pk.v;
        }
    } else {
#pragma unroll
        for (int kk = 0; kk < NK; ++kk)
            af[kk] = *(const bf16x8*)((const ushort*)X + (size_t)arow * K_DIM + kk * 32 + lk);
    }

    f32x4 acc[6];
#pragma unroll
    for (int nn = 0; nn < 6; ++nn) { acc[nn][0] = 0.f; acc[nn][1] = 0.f; acc[nn][2] = 0.f; acc[nn][3] = 0.f; }
#pragma unroll
    for (int nn = 0; nn < 6; ++nn)
#pragma unroll
        for (int kk = 0; kk < NK; ++kk)
            acc[nn] = __builtin_amdgcn_mfma_f32_16x16x32_bf16(af[kk], wf[nn][kk], acc[nn], 0, 0, 0);

    float bcol[6], gcol[6], ncol[6];
    if (EPI == 2 || EPI == 5) {
#pragma unroll
        for (int nn = 0; nn < 6; ++nn) {
            bcol[nn] = bias[nn * 16 + lrow];
            gcol[nn] = g[nn * 16 + lrow];
            ncol[nn] = beta[nn * 16 + lrow];
        }
    }

    ushort* tw = &Tt[(EPI == 5) ? wv * 16 * 104 : 0];
    const int rbase = grp * 16 + (lane >> 4) * 4;
#pragma unroll
    for (int reg = 0; reg < 4; ++reg) {
        const int row = rbase + reg;
        float v[6];
#pragma unroll
        for (int nn = 0; nn < 6; ++nn) {
            v[nn] = acc[nn][reg];
            if (EPI == 2 || EPI == 5) v[nn] += bcol[nn];
            if (EPI == 5) v[nn] = gelu_f(v[nn]);
        }
        if (EPI == 2 || EPI == 5) {
            float s = 0.f, s2 = 0.f;
#pragma unroll
            for (int nn = 0; nn < 6; ++nn) { s += v[nn]; s2 += v[nn] * v[nn]; }
#pragma unroll
            for (int off = 1; off < 16; off <<= 1) { s += __shfl_xor(s, off); s2 += __shfl_xor(s2, off); }
            float mean = s * (1.f / 96.f);
            float var = s2 * (1.f / 96.f) - mean * mean;
            float rs = rsqrtf(var + LN_EPS_F);
#pragma unroll
            for (int nn = 0; nn < 6; ++nn) v[nn] = (v[nn] - mean) * rs * gcol[nn] + ncol[nn];
        }
        if constexpr (EPI == 5) {
            const int rl = (lane >> 4) * 4 + reg;
#pragma unroll
            for (int nn = 0; nn < 6; ++nn)
                tw[rl * 104 + nn * 16 + lrow] = f2bf(v[nn]);
        } else if constexpr (EPI == 0) {
            float dvr = dinvp[row];
#pragma unroll
            for (int nn = 0; nn < 6; ++nn)
                ((ushort*)outv)[(size_t)row * 96 + nn * 16 + lrow] = f2bf(v[nn] * dvr);
        } else {  // EPI 2 -> bf16 hb
#pragma unroll
            for (int nn = 0; nn < 6; ++nn)
                ((ushort*)outv)[(size_t)row * 96 + nn * 16 + lrow] = f2bf(v[nn]);
        }
    }

    if constexpr (EPI == 5) {
        asm volatile("s_waitcnt lgkmcnt(0)" ::: "memory");
        __builtin_amdgcn_sched_barrier(0);
        bf16x8 tf[3], w2f[3];
#pragma unroll
        for (int kk = 0; kk < 3; ++kk) {
            tf[kk]  = *(const bf16x8*)(&tw[lrow * 104 + kk * 32 + lk]);
            w2f[kk] = *(const bf16x8*)(&w2t[lrow * 96 + kk * 32 + lk]);
        }
        f32x4 acc2;
        acc2[0] = 0.f; acc2[1] = 0.f; acc2[2] = 0.f; acc2[3] = 0.f;
#pragma unroll
        for (int kk = 0; kk < 3; ++kk)
            acc2 = __builtin_amdgcn_mfma_f32_16x16x32_bf16(tf[kk], w2f[kk], acc2, 0, 0, 0);
        const int c = lane & 15;
        if (c < C_DIM) {
#pragma unroll
            for (int reg = 0; reg < 4; ++reg) {
                int nrow = grp * 16 + (lane >> 4) * 4 + reg;
                ((float*)outv)[(size_t)nrow * C_DIM + c] = acc2[reg] + b2[c];
            }
        }
    }
}

// ---------- fused PE: hb += rho2(relu(rho1(phi2(sum_k relu(z@phi_w1))))) ----------

__launch_bounds__(256)
__global__ void k_pe(const float* __restrict__ eigvecs, const float* __restrict__ eigvals,
                     const float* __restrict__ pe_eps, const float* __restrict__ phi_w1,
                     const ushort* __restrict__ w_phi2, const ushort* __restrict__ w_rho1,
                     const ushort* __restrict__ w_rho2, const float* __restrict__ rho_b1,
                     const float* __restrict__ rho_b2, ushort* __restrict__ hb) {
    constexpr int KP = 104;
    __shared__ ushort WL[96 * KP];
    __shared__ ushort T[64 * KP];
    const int t = threadIdx.x;
    const int base = blockIdx.x * 64;

    for (int i = t; i < 96 * 12; i += 256) {
        int n = i / 12, kc = (i - n * 12) * 8;
        *(uint4*)(&WL[n * KP + kc]) = *(const uint4*)(&w_phi2[n * 96 + kc]);
    }
    {
        int r = t >> 2, jg = t & 3;
        int row = base + r;
        float s[24];
#pragma unroll
        for (int j = 0; j < 24; ++j) s[j] = 0.f;
        if (row < N_NODES) {
            float w0[24], w1v[24];
#pragma unroll
            for (int j = 0; j < 24; ++j) { w0[j] = phi_w1[jg * 24 + j]; w1v[j] = phi_w1[96 + jg * 24 + j]; }
            for (int k = 0; k < K_EIG; ++k) {
                float a = eigvecs[(size_t)row * K_EIG + k];
                float b = eigvals[(size_t)row * K_EIG + k] + pe_eps[k];
#pragma unroll
                for (int j = 0; j < 24; ++j) s[j] += fmaxf(fmaf(a, w0[j], b * w1v[j]), 0.f);
            }
        }
#pragma unroll
        for (int j = 0; j < 12; ++j) {
            unsigned pk = (unsigned)f2bf(s[2 * j]) | ((unsigned)f2bf(s[2 * j + 1]) << 16);
            *(unsigned*)(&T[r * KP + jg * 24 + 2 * j]) = pk;
        }
    }
    __syncthreads();

    const int lane = t & 63, w = t >> 6;
    const int lrow = lane & 15, lk = (lane >> 4) * 8;
    const int rsub = (lane >> 4) * 4;
    float bc2[6], bc3[6];
#pragma unroll
    for (int nn = 0; nn < 6; ++nn) { bc2[nn] = rho_b1[nn * 16 + lrow]; bc3[nn] = rho_b2[nn * 16 + lrow]; }

    f32x4 acc[6];

    // stage 1: T @ phi_w2 -> T
    {
        bf16x8 af[3];
#pragma unroll
        for (int kk = 0; kk < 3; ++kk) af[kk] = *(const bf16x8*)(&T[(w * 16 + lrow) * KP + kk * 32 + lk]);
#pragma unroll
        for (int nn = 0; nn < 6; ++nn) { acc[nn][0] = 0.f; acc[nn][1] = 0.f; acc[nn][2] = 0.f; acc[nn][3] = 0.f; }
#pragma unroll
        for (int nn = 0; nn < 6; ++nn)
#pragma unroll
            for (int kk = 0; kk < 3; ++kk)
                acc[nn] = __builtin_amdgcn_mfma_f32_16x16x32_bf16(
                    af[kk], *(const bf16x8*)(&WL[(nn * 16 + lrow) * KP + kk * 32 + lk]), acc[nn], 0, 0, 0);
        __syncthreads();
#pragma unroll
        for (int reg = 0; reg < 4; ++reg)
#pragma unroll
            for (int nn = 0; nn < 6; ++nn)
                T[(w * 16 + rsub + reg) * KP + nn * 16 + lrow] = f2bf(acc[nn][reg]);
        for (int i = t; i < 96 * 12; i += 256) {
            int n = i / 12, kc = (i - n * 12) * 8;
            *(uint4*)(&WL[n * KP + kc]) = *(const uint4*)(&w_rho1[n * 96 + kc]);
        }
        __syncthreads();
    }

    // stage 2: relu(T @ rho_w1 + b1) -> T
    {
        bf16x8 af[3];
#pragma unroll
        for (int kk = 0; kk < 3; ++kk) af[kk] = *(const bf16x8*)(&T[(w * 16 + lrow) * KP + kk * 32 + lk]);
#pragma unroll
        for (int nn = 0; nn < 6; ++nn) { acc[nn][0] = 0.f; acc[nn][1] = 0.f; acc[nn][2] = 0.f; acc[nn][3] = 0.f; }
#pragma unroll
        for (int nn = 0; nn < 6; ++nn)
#pragma unroll
            for (int kk = 0; kk < 3; ++kk)
                acc[nn] = __builtin_amdgcn_mfma_f32_16x16x32_bf16(
                    af[kk], *(const bf16x8*)(&WL[(nn * 16 + lrow) * KP + kk * 32 + lk]), acc[nn], 0, 0, 0);
        __syncthreads();
#pragma unroll
        for (int reg = 0; reg < 4; ++reg)
#pragma unroll
            for (int nn = 0; nn < 6; ++nn)
                T[(w * 16 + rsub + reg) * KP + nn * 16 + lrow] = f2bf(fmaxf(acc[nn][reg] + bc2[nn], 0.f));
        for (int i = t; i < 96 * 12; i += 256) {
            int n = i / 12, kc = (i - n * 12) * 8;
            *(uint4*)(&WL[n * KP + kc]) = *(const uint4*)(&w_rho2[n * 96 + kc]);
        }
        __syncthreads();
    }

    // stage 3: hb = bf16(hb + T @ rho_w2 + b2)
    {
        bf16x8 af[3];
#pragma unroll
        for (int kk = 0; kk < 3; ++kk) af[kk] = *(const bf16x8*)(&T[(w * 16 + lrow) * KP + kk * 32 + lk]);
#pragma unroll
        for (int nn = 0; nn < 6; ++nn) { acc[nn][0] = 0.f; acc[nn][1] = 0.f; acc[nn][2] = 0.f; acc[nn][3] = 0.f; }
#pragma unroll
        for (int nn = 0; nn < 6; ++nn)
#pragma unroll
            for (int kk = 0; kk < 3; ++kk)
                acc[nn] = __builtin_amdgcn_mfma_f32_16x16x32_bf16(
                    af[kk], *(const bf16x8*)(&WL[(nn * 16 + lrow) * KP + kk * 32 + lk]), acc[nn], 0, 0, 0);
#pragma unroll
        for (int reg = 0; reg < 4; ++reg) {
            int row = base + w * 16 + rsub + reg;
            if (row < N_NODES) {
#pragma unroll
                for (int nn = 0; nn < 6; ++nn) {
                    size_t idx = (size_t)row * 96 + nn * 16 + lrow;
                    float hv = bf2f(hb[idx]) + acc[nn][reg] + bc3[nn];
                    hb[idx] = f2bf(hv);
                }
            }
        }
    }
}

// ---------- GCN aggregation: row-per-16-lane-group, 16-deep gather batches ----------

#define GA_EDGE(c) { uint3 gv = *(const uint3*)(&xw[(c) * 48 + f * 3]); \
    a[0] += bflo(gv.x); a[1] += bfhi(gv.x); \
    a[2] += bflo(gv.y); a[3] += bfhi(gv.y); \
    a[4] += bflo(gv.z); a[5] += bfhi(gv.z); }

__launch_bounds__(256)
__global__ void k_agg(const unsigned int* __restrict__ xw, const int* __restrict__ rowst,
                      const int* __restrict__ csr, const float* __restrict__ dinv,
                      const float* __restrict__ bias, const float* __restrict__ g,
                      const float* __restrict__ beta, ushort* __restrict__ hb) {
    const int lane = threadIdx.x & 63, wid = threadIdx.x >> 6;
    const int f = lane & 15;      // feature lane: features f*6..f*6+5
    const int eg = lane >> 4;     // row subgroup 0..3
    float bb[6], gg[6], be[6];
#pragma unroll
    for (int j = 0; j < 6; ++j) { bb[j] = bias[f * 6 + j]; gg[j] = g[f * 6 + j]; be[j] = beta[f * 6 + j]; }
    const int w = blockIdx.x * 4 + wid, stride = gridDim.x * 4;
    for (int base = w * 4; base < N_NODES; base += stride * 4) {
        const int row = base + eg;   // N_NODES % 4 == 0 -> always valid
        int rs = rowst[row], re = rowst[row + 1];
        float dv = dinv[row];
        uint3 sv = *(const uint3*)(&xw[row * 48 + f * 3]);
        float a[6];
        a[0] = bflo(sv.x); a[1] = bfhi(sv.x);
        a[2] = bflo(sv.y); a[3] = bfhi(sv.y);
        a[4] = bflo(sv.z); a[5] = bfhi(sv.z);
        int i = rs;
        for (; i + 15 < re; i += 16) {
            int c[16];
#pragma unroll
            for (int u = 0; u < 16; ++u) c[u] = csr[i + u];
            uint3 vv[16];
#pragma unroll
            for (int u = 0; u < 16; ++u) vv[u] = *(const uint3*)(&xw[c[u] * 48 + f * 3]);
#pragma unroll
            for (int u = 0; u < 16; ++u) {
                a[0] += bflo(vv[u].x); a[1] += bfhi(vv[u].x);
                a[2] += bflo(vv[u].y); a[3] += bfhi(vv[u].y);
                a[4] += bflo(vv[u].z); a[5] += bfhi(vv[u].z);
            }
        }
        for (; i + 3 < re; i += 4) {
            int c0 = csr[i], c1 = csr[i + 1], c2 = csr[i + 2], c3 = csr[i + 3];
            GA_EDGE(c0); GA_EDGE(c1); GA_EDGE(c2); GA_EDGE(c3);
        }
        for (; i < re; ++i) {
            int c0 = csr[i];
            GA_EDGE(c0);
        }
        float s = 0.f, s2 = 0.f;
#pragma unroll
        for (int j = 0; j < 6; ++j) {
            a[j] = fmaf(a[j], dv, bb[j]);
            a[j] = gelu_f(a[j]);
            s += a[j]; s2 += a[j] * a[j];
        }
#pragma unroll
        for (int off = 1; off < 16; off <<= 1) { s += __shfl_xor(s, off); s2 += __shfl_xor(s2, off); }
        float mean = s * (1.f / 96.f);
        float var = s2 * (1.f / 96.f) - mean * mean;
        float rs_ = rsqrtf(var + LN_EPS_F);
        unsigned int* hbp = (unsigned int*)(hb + (size_t)row * 96 + f * 6);
        unsigned hv0 = hbp[0], hv1 = hbp[1], hv2 = hbp[2];
        float v0 = bflo(hv0) + (a[0] - mean) * rs_ * gg[0] + be[0];
        float v1 = bfhi(hv0) + (a[1] - mean) * rs_ * gg[1] + be[1];
        float v2 = bflo(hv1) + (a[2] - mean) * rs_ * gg[2] + be[2];
        float v3 = bfhi(hv1) + (a[3] - mean) * rs_ * gg[3] + be[3];
        float v4 = bflo(hv2) + (a[4] - mean) * rs_ * gg[4] + be[4];
        float v5 = bfhi(hv2) + (a[5] - mean) * rs_ * gg[5] + be[5];
        hbp[0] = (unsigned)f2bf(v0) | ((unsigned)f2bf(v1) << 16);
        hbp[1] = (unsigned)f2bf(v2) | ((unsigned)f2bf(v3) << 16);
        hbp[2] = (unsigned)f2bf(v4) | ((unsigned)f2bf(v5) << 16);
    }
}

// ---------- host ----------

extern "C" void kernel_launch(void* const* d_in, const int* in_sizes, int n_in,
                              void* d_out, int out_size, void* d_ws, size_t ws_size,
                              hipStream_t stream) {
    (void)in_sizes; (void)n_in; (void)out_size; (void)ws_size;
    const float* x       = (const float*)d_in[0];
    const int*   eidx    = (const int*)d_in[1];
    const float* eigvecs = (const float*)d_in[2];
    const float* eigvals = (const float*)d_in[3];
    const float* enc_W   = (const float*)d_in[4];
    const float* enc_b   = (const float*)d_in[5];
    const float* in_g    = (const float*)d_in[6];
    const float* in_b    = (const float*)d_in[7];
    const float* phi_w1  = (const float*)d_in[8];
    const float* phi_w2  = (const float*)d_in[9];
    const float* rho_w1  = (const float*)d_in[10];
    const float* rho_b1  = (const float*)d_in[11];
    const float* rho_w2  = (const float*)d_in[12];
    const float* rho_b2  = (const float*)d_in[13];
    const float* pe_eps  = (const float*)d_in[14];
    const float* conv_W  = (const float*)d_in[15];
    const float* conv_b  = (const float*)d_in[16];
    const float* norm_g  = (const float*)d_in[17];
    const float* norm_b  = (const float*)d_in[18];
    const float* head_w1 = (const float*)d_in[19];
    const float* head_b1 = (const float*)d_in[20];
    const float* head_g  = (const float*)d_in[21];
    const float* head_b  = (const float*)d_in[22];
    const float* head_w2 = (const float*)d_in[23];
    const float* head_b2 = (const float*)d_in[24];
    float* out = (float*)d_out;

    const int* src = eidx;
    const int* dst = eidx + N_EDGES;

    char* ws = (char*)d_ws;
    size_t off = 0;
    auto alloc = [&](size_t bytes) {
        void* p = ws + off;
        off += (bytes + 255) & ~(size_t)255;
        return p;
    };
    ushort*   hb    = (ushort*)alloc(sizeof(ushort) * (size_t)N_NODES * H_DIM);
    ushort*   bufA  = (ushort*)alloc(sizeof(ushort) * (size_t)N_NODES * H_DIM);
    ushort*   wbf   = (ushort*)alloc(sizeof(ushort) * (12288 + 8 * 9216 + 1536));
    int*      rowst = (int*)alloc(sizeof(int) * (N_NODES + 1));
    float*    dinv  = (float*)alloc(sizeof(float) * N_NODES);
    int*      csr   = (int*)alloc(sizeof(int) * N_EDGES);
    int*      cm    = (int*)alloc(sizeof(int) * (NBK * NPB + 1));
    unsigned* eb    = (unsigned*)bufA;  // alias: eb (3.2MB) dead before GEMMs use bufA

    const int gb = (N_NODES / 16 + 3) / 4;         // 782 blocks, wave-per-16-row-group
    const int pb = (N_NODES + 63) / 64;            // 782
    const int ab = 1563;                           // agg grid: 2 balanced sweeps
    const int prep_n = 12288 + 8 * 9216 + 1536;

    WSrc wsrc;
    wsrc.p[0] = enc_W; wsrc.p[1] = phi_w2; wsrc.p[2] = rho_w1; wsrc.p[3] = rho_w2;
    for (int l = 0; l < 4; ++l) wsrc.p[4 + l] = conv_W + (size_t)l * 9216;
    wsrc.p[8] = head_w1; wsrc.p[9] = head_w2;
    k_prep<<<(prep_n + 255) / 256, 256, 0, stream>>>(wsrc, wbf);

    // bucketed CSR build (packed 4B eb)
    k_binA<<<NPB, 256, 0, stream>>>(dst, cm);
    k_binB<<<1, 1024, 0, stream>>>(cm, NBK * NPB);
    k_binC<<<NPB, 256, 0, stream>>>(src, dst, cm, eb);
    k_binD<<<NBK, 1024, 0, stream>>>(eb, cm, rowst, dinv, csr);

    const ushort* w_enc  = wbf;
    const ushort* w_head = wbf + 12288 + 7 * 9216;
    const ushort* w_2t   = wbf + 12288 + 8 * 9216;

    // encoder: hb = bf16(LN(x @ enc_W + enc_b))
    k_gemm<IN_DIM, float, 2><<<gb, 256, 0, stream>>>(x, w_enc, enc_b, in_g, in_b,
                                                     nullptr, nullptr, nullptr, hb);

    // fused PE chain: hb += PE
    k_pe<<<pb, 256, 0, stream>>>(eigvecs, eigvals, pe_eps, phi_w1,
                                 wbf + 12288, wbf + 12288 + 9216, wbf + 12288 + 2 * 9216,
                                 rho_b1, rho_b2, hb);

    // GCN layers: xw' = (hb @ conv_W) * dinv[row]; pull agg + epilogue, bf16 residual
    for (int l = 0; l < L_LAYERS; ++l) {
        k_gemm<96, ushort, 0><<<gb, 256, 0, stream>>>(hb, wbf + 12288 + (size_t)(3 + l) * 9216,
                                                      nullptr, nullptr, nullptr, dinv,
                                                      nullptr, nullptr, bufA);
        k_agg<<<ab, 256, 0, stream>>>((const unsigned int*)bufA, rowst, csr, dinv,
                                      conv_b + (size_t)l * 96, norm_g + (size_t)l * 96,
                                      norm_b + (size_t)l * 96, hb);
    }

    // fused head: out = LN(gelu(hb@w1+b1)) @ w2 + b2 (second MFMA)
    k_gemm<96, ushort, 5><<<gb, 256, 0, stream>>>(hb, w_head, head_b1, head_g, head_b,
                                                  nullptr, w_2t, head_b2, out);
}

// Round 14
// 271.200 us; speedup vs baseline: 1.0843x; 1.0843x over previous
//
#include <hip/hip_runtime.h>
#include <hip/hip_bf16.h>

#define N_NODES 50000
#define N_EDGES 800000
#define IN_DIM  128
#define H_DIM   96
#define C_DIM   10
#define L_LAYERS 4
#define K_EIG   16
#define LN_EPS_F 1e-5f

// edge-partition geometry (round-8 proven build, packed 4B payload)
#define EPB 4096                 // edges per partition block
#define NPB 196                  // ceil(N_EDGES / EPB)
#define BKT 512                  // dst nodes per bucket
#define NBK 98                   // ceil(N_NODES / BKT)

typedef __attribute__((ext_vector_type(8))) short bf16x8;
typedef __attribute__((ext_vector_type(4))) float f32x4;

// ---------- device helpers ----------

__device__ __forceinline__ float gelu_f(float x) {
    return 0.5f * x * (1.0f + erff(x * 0.7071067811865476f));
}

__device__ __forceinline__ ushort f2bf(float f) {
    union { float f; unsigned int u; } v; v.f = f;
    unsigned int r = v.u + 0x7fffu + ((v.u >> 16) & 1u);
    return (ushort)(r >> 16);
}

__device__ __forceinline__ float bflo(unsigned int v) { return __uint_as_float(v << 16); }
__device__ __forceinline__ float bfhi(unsigned int v) { return __uint_as_float(v & 0xffff0000u); }
__device__ __forceinline__ float bf2f(ushort u) { return __uint_as_float(((unsigned)u) << 16); }

// ---------- graph preprocessing: bucketed CSR build ----------

__global__ void k_binA(const int* __restrict__ dst, int* __restrict__ cntmat) {
    __shared__ int hist[NBK];
    for (int i = threadIdx.x; i < NBK; i += 256) hist[i] = 0;
    __syncthreads();
    const int e0 = blockIdx.x * EPB;
    for (int i = threadIdx.x; i < EPB; i += 256) {
        int e = e0 + i;
        if (e < N_EDGES) atomicAdd(&hist[dst[e] >> 9], 1);
    }
    __syncthreads();
    for (int i = threadIdx.x; i < NBK; i += 256)
        cntmat[i * NPB + blockIdx.x] = hist[i];
}

__global__ void k_binB(int* __restrict__ cm, int n) {
    __shared__ int wsum[16];
    const int tid = threadIdx.x, lane = tid & 63, wid = tid >> 6;
    int carry = 0;
    for (int base = 0; base < n; base += 1024) {
        int i = base + tid;
        int v = (i < n) ? cm[i] : 0;
        int s = v;
#pragma unroll
        for (int off = 1; off < 64; off <<= 1) {
            int x = __shfl_up(s, off);
            if (lane >= off) s += x;
        }
        if (lane == 63) wsum[wid] = s;
        __syncthreads();
        if (tid < 64) {
            int ws = (lane < 16) ? wsum[lane] : 0;
#pragma unroll
            for (int off = 1; off < 16; off <<= 1) {
                int x = __shfl_up(ws, off);
                if (lane >= off) ws += x;
            }
            if (lane < 16) wsum[lane] = ws;
        }
        __syncthreads();
        int woff = (wid > 0) ? wsum[wid - 1] : 0;
        if (i < n) cm[i] = carry + woff + s - v;
        int tot = wsum[15];
        __syncthreads();
        carry += tot;
    }
    if (tid == 0) cm[n] = carry;
}

// C: partition edges into bucket-grouped packed array eb[] ((dstLocal<<16)|src)
__global__ void k_binC(const int* __restrict__ src, const int* __restrict__ dst,
                       const int* __restrict__ offs, unsigned int* __restrict__ eb) {
    __shared__ int cur[NBK];
    for (int i = threadIdx.x; i < NBK; i += 256) cur[i] = offs[i * NPB + blockIdx.x];
    __syncthreads();
    const int e0 = blockIdx.x * EPB;
    for (int i = threadIdx.x; i < EPB; i += 256) {
        int e = e0 + i;
        if (e < N_EDGES) {
            int d = dst[e];
            int slot = atomicAdd(&cur[d >> 9], 1);
            eb[slot] = ((unsigned)(d & (BKT - 1)) << 16) | (unsigned)src[e];
        }
    }
}

// D: per-bucket fine CSR fill + rowst + dinv
__global__ void k_binD(const unsigned int* __restrict__ eb, const int* __restrict__ offs,
                       int* __restrict__ rowst, float* __restrict__ dinv,
                       int* __restrict__ csr) {
    __shared__ int cnt[BKT];
    __shared__ int wsum[16];
    const int b = blockIdx.x, t = threadIdx.x;
    const int ebeg = offs[b * NPB], eend = offs[(b + 1) * NPB];
    for (int i = t; i < BKT; i += 1024) cnt[i] = 0;
    __syncthreads();
    for (int i = ebeg + t; i < eend; i += 1024)
        atomicAdd(&cnt[eb[i] >> 16], 1);
    __syncthreads();
    const int lane = t & 63, wid = t >> 6;
    int v = 0, s = 0;
    if (t < BKT) {
        v = cnt[t]; s = v;
#pragma unroll
        for (int off = 1; off < 64; off <<= 1) {
            int x = __shfl_up(s, off);
            if (lane >= off) s += x;
        }
        if (lane == 63) wsum[wid] = s;
    }
    __syncthreads();
    if (t < 64) {
        int ws = (lane < 8) ? wsum[lane] : 0;
#pragma unroll
        for (int off = 1; off < 8; off <<= 1) {
            int x = __shfl_up(ws, off);
            if (lane >= off) ws += x;
        }
        if (lane < 8) wsum[lane] = ws;
    }
    __syncthreads();
    if (t < BKT) {
        int woff = (wid > 0) ? wsum[wid - 1] : 0;
        int excl = ebeg + woff + s - v;
        int row = b * BKT + t;
        if (row < N_NODES) {
            rowst[row] = excl;
            dinv[row] = rsqrtf((float)v + 1.0f);
        }
        cnt[t] = excl;
    }
    __syncthreads();
    for (int i = ebeg + t; i < eend; i += 1024) {
        unsigned e = eb[i];
        int p = atomicAdd(&cnt[e >> 16], 1);
        csr[p] = (int)(e & 0xFFFFu);
    }
    if (b == 0 && t == 0) rowst[N_NODES] = N_EDGES;
}

// ---------- weight prep: transpose + bf16 ----------

struct WSrc { const float* p[10]; };

__global__ void k_prep(WSrc ws, ushort* __restrict__ out) {
    int idx = blockIdx.x * 256 + threadIdx.x;
    if (idx < 12288) {
        int n = idx >> 7, k = idx & 127;
        out[idx] = f2bf(ws.p[0][k * 96 + n]);
    } else if (idx < 12288 + 8 * 9216) {
        int j = idx - 12288;
        int m = j / 9216, r = j - m * 9216;
        int n = r / 96, k = r - n * 96;
        out[idx] = f2bf(ws.p[m + 1][k * 96 + n]);
    } else if (idx < 12288 + 8 * 9216 + 1536) {
        int j = idx - 12288 - 8 * 9216;
        int c = j / 96, k = j - c * 96;
        out[idx] = (c < C_DIM) ? f2bf(ws.p[9][k * C_DIM + c]) : (ushort)0;
    }
}

// ---------- MFMA GEMM, wave-per-16-rows, operands via registers ----------
// EPI 0: (.*dinv[row]) -> bf16 out         (conv xw', norm folded)
// EPI 2: LN(.+bias; g,beta) -> bf16 out    (encoder -> hb)
// EPI 5: head: t = LN(gelu(.+bias); g,beta); out = t @ W2 + b2 via 2nd MFMA
//   D mapping (HW-verified): row=(lane>>4)*4+reg, col=lane&15

template <int K_DIM, typename XT, int EPI>
__launch_bounds__(256)
__global__ void k_gemm(const XT* __restrict__ X, const ushort* __restrict__ Wt,
                       const float* __restrict__ bias, const float* __restrict__ g,
                       const float* __restrict__ beta, const float* __restrict__ dinvp,
                       const ushort* __restrict__ w2t, const float* __restrict__ b2,
                       void* __restrict__ outv) {
    constexpr int NK = K_DIM / 32;
    __shared__ ushort Tt[(EPI == 5) ? 4 * 16 * 104 : 4];
    const int lane = threadIdx.x & 63, wv = threadIdx.x >> 6;
    const int lrow = lane & 15, lk = (lane >> 4) * 8;
    const int grp = blockIdx.x * 4 + wv;
    if (grp >= N_NODES / 16) return;

    bf16x8 wf[6][NK];
#pragma unroll
    for (int nn = 0; nn < 6; ++nn)
#pragma unroll
        for (int kk = 0; kk < NK; ++kk)
            wf[nn][kk] = *(const bf16x8*)(&Wt[(size_t)(nn * 16 + lrow) * K_DIM + kk * 32 + lk]);

    bf16x8 af[NK];
    const int arow = grp * 16 + lrow;
    if constexpr (sizeof(XT) == 4) {
#pragma unroll
        for (int kk = 0; kk < NK; ++kk) {
            const float4* p = (const float4*)((const float*)X + (size_t)arow * K_DIM + kk * 32 + lk);
            float4 a = p[0], b = p[1];
            union { bf16x8 v; unsigned u[4]; } pk;
            pk.u[0] = (unsigned)f2bf(a.x) | ((unsigned)f2bf(a.y) << 16);
            pk.u[1] = (unsigned)f2bf(a.z) | ((unsigned)f2bf(a.w) << 16);
            pk.u[2] = (unsigned)f2bf(b.x) | ((unsigned)f2bf(b.y) << 16);
            pk.u[3] = (unsigned)f2bf(b.z) | ((unsigned)f2bf(b.w) << 16);
            af[kk] = pk.v;
        }
    } else {
#pragma unroll
        for (int kk = 0; kk < NK; ++kk)
            af[kk] = *(const bf16x8*)((const ushort*)X + (size_t)arow * K_DIM + kk * 32 + lk);
    }

    f32x4 acc[6];
#pragma unroll
    for (int nn = 0; nn < 6; ++nn) { acc[nn][0] = 0.f; acc[nn][1] = 0.f; acc[nn][2] = 0.f; acc[nn][3] = 0.f; }
#pragma unroll
    for (int nn = 0; nn < 6; ++nn)
#pragma unroll
        for (int kk = 0; kk < NK; ++kk)
            acc[nn] = __builtin_amdgcn_mfma_f32_16x16x32_bf16(af[kk], wf[nn][kk], acc[nn], 0, 0, 0);

    float bcol[6], gcol[6], ncol[6];
    if (EPI == 2 || EPI == 5) {
#pragma unroll
        for (int nn = 0; nn < 6; ++nn) {
            bcol[nn] = bias[nn * 16 + lrow];
            gcol[nn] = g[nn * 16 + lrow];
            ncol[nn] = beta[nn * 16 + lrow];
        }
    }

    ushort* tw = &Tt[(EPI == 5) ? wv * 16 * 104 : 0];
    const int rbase = grp * 16 + (lane >> 4) * 4;
#pragma unroll
    for (int reg = 0; reg < 4; ++reg) {
        const int row = rbase + reg;
        float v[6];
#pragma unroll
        for (int nn = 0; nn < 6; ++nn) {
            v[nn] = acc[nn][reg];
            if (EPI == 2 || EPI == 5) v[nn] += bcol[nn];
            if (EPI == 5) v[nn] = gelu_f(v[nn]);
        }
        if (EPI == 2 || EPI == 5) {
            float s = 0.f, s2 = 0.f;
#pragma unroll
            for (int nn = 0; nn < 6; ++nn) { s += v[nn]; s2 += v[nn] * v[nn]; }
#pragma unroll
            for (int off = 1; off < 16; off <<= 1) { s += __shfl_xor(s, off); s2 += __shfl_xor(s2, off); }
            float mean = s * (1.f / 96.f);
            float var = s2 * (1.f / 96.f) - mean * mean;
            float rs = rsqrtf(var + LN_EPS_F);
#pragma unroll
            for (int nn = 0; nn < 6; ++nn) v[nn] = (v[nn] - mean) * rs * gcol[nn] + ncol[nn];
        }
        if constexpr (EPI == 5) {
            const int rl = (lane >> 4) * 4 + reg;
#pragma unroll
            for (int nn = 0; nn < 6; ++nn)
                tw[rl * 104 + nn * 16 + lrow] = f2bf(v[nn]);
        } else if constexpr (EPI == 0) {
            float dvr = dinvp[row];
#pragma unroll
            for (int nn = 0; nn < 6; ++nn)
                ((ushort*)outv)[(size_t)row * 96 + nn * 16 + lrow] = f2bf(v[nn] * dvr);
        } else {  // EPI 2 -> bf16 hb
#pragma unroll
            for (int nn = 0; nn < 6; ++nn)
                ((ushort*)outv)[(size_t)row * 96 + nn * 16 + lrow] = f2bf(v[nn]);
        }
    }

    if constexpr (EPI == 5) {
        asm volatile("s_waitcnt lgkmcnt(0)" ::: "memory");
        __builtin_amdgcn_sched_barrier(0);
        bf16x8 tf[3], w2f[3];
#pragma unroll
        for (int kk = 0; kk < 3; ++kk) {
            tf[kk]  = *(const bf16x8*)(&tw[lrow * 104 + kk * 32 + lk]);
            w2f[kk] = *(const bf16x8*)(&w2t[lrow * 96 + kk * 32 + lk]);
        }
        f32x4 acc2;
        acc2[0] = 0.f; acc2[1] = 0.f; acc2[2] = 0.f; acc2[3] = 0.f;
#pragma unroll
        for (int kk = 0; kk < 3; ++kk)
            acc2 = __builtin_amdgcn_mfma_f32_16x16x32_bf16(tf[kk], w2f[kk], acc2, 0, 0, 0);
        const int c = lane & 15;
        if (c < C_DIM) {
#pragma unroll
            for (int reg = 0; reg < 4; ++reg) {
                int nrow = grp * 16 + (lane >> 4) * 4 + reg;
                ((float*)outv)[(size_t)nrow * C_DIM + c] = acc2[reg] + b2[c];
            }
        }
    }
}

// ---------- fused PE: hb += rho2(relu(rho1(phi2(sum_k relu(z@phi_w1))))) ----------

__launch_bounds__(256)
__global__ void k_pe(const float* __restrict__ eigvecs, const float* __restrict__ eigvals,
                     const float* __restrict__ pe_eps, const float* __restrict__ phi_w1,
                     const ushort* __restrict__ w_phi2, const ushort* __restrict__ w_rho1,
                     const ushort* __restrict__ w_rho2, const float* __restrict__ rho_b1,
                     const float* __restrict__ rho_b2, ushort* __restrict__ hb) {
    constexpr int KP = 104;
    __shared__ ushort WL[96 * KP];
    __shared__ ushort T[64 * KP];
    const int t = threadIdx.x;
    const int base = blockIdx.x * 64;

    for (int i = t; i < 96 * 12; i += 256) {
        int n = i / 12, kc = (i - n * 12) * 8;
        *(uint4*)(&WL[n * KP + kc]) = *(const uint4*)(&w_phi2[n * 96 + kc]);
    }
    {
        int r = t >> 2, jg = t & 3;
        int row = base + r;
        float s[24];
#pragma unroll
        for (int j = 0; j < 24; ++j) s[j] = 0.f;
        if (row < N_NODES) {
            float w0[24], w1v[24];
#pragma unroll
            for (int j = 0; j < 24; ++j) { w0[j] = phi_w1[jg * 24 + j]; w1v[j] = phi_w1[96 + jg * 24 + j]; }
            for (int k = 0; k < K_EIG; ++k) {
                float a = eigvecs[(size_t)row * K_EIG + k];
                float b = eigvals[(size_t)row * K_EIG + k] + pe_eps[k];
#pragma unroll
                for (int j = 0; j < 24; ++j) s[j] += fmaxf(fmaf(a, w0[j], b * w1v[j]), 0.f);
            }
        }
#pragma unroll
        for (int j = 0; j < 12; ++j) {
            unsigned pk = (unsigned)f2bf(s[2 * j]) | ((unsigned)f2bf(s[2 * j + 1]) << 16);
            *(unsigned*)(&T[r * KP + jg * 24 + 2 * j]) = pk;
        }
    }
    __syncthreads();

    const int lane = t & 63, w = t >> 6;
    const int lrow = lane & 15, lk = (lane >> 4) * 8;
    const int rsub = (lane >> 4) * 4;
    float bc2[6], bc3[6];
#pragma unroll
    for (int nn = 0; nn < 6; ++nn) { bc2[nn] = rho_b1[nn * 16 + lrow]; bc3[nn] = rho_b2[nn * 16 + lrow]; }

    f32x4 acc[6];

    // stage 1: T @ phi_w2 -> T
    {
        bf16x8 af[3];
#pragma unroll
        for (int kk = 0; kk < 3; ++kk) af[kk] = *(const bf16x8*)(&T[(w * 16 + lrow) * KP + kk * 32 + lk]);
#pragma unroll
        for (int nn = 0; nn < 6; ++nn) { acc[nn][0] = 0.f; acc[nn][1] = 0.f; acc[nn][2] = 0.f; acc[nn][3] = 0.f; }
#pragma unroll
        for (int nn = 0; nn < 6; ++nn)
#pragma unroll
            for (int kk = 0; kk < 3; ++kk)
                acc[nn] = __builtin_amdgcn_mfma_f32_16x16x32_bf16(
                    af[kk], *(const bf16x8*)(&WL[(nn * 16 + lrow) * KP + kk * 32 + lk]), acc[nn], 0, 0, 0);
        __syncthreads();
#pragma unroll
        for (int reg = 0; reg < 4; ++reg)
#pragma unroll
            for (int nn = 0; nn < 6; ++nn)
                T[(w * 16 + rsub + reg) * KP + nn * 16 + lrow] = f2bf(acc[nn][reg]);
        for (int i = t; i < 96 * 12; i += 256) {
            int n = i / 12, kc = (i - n * 12) * 8;
            *(uint4*)(&WL[n * KP + kc]) = *(const uint4*)(&w_rho1[n * 96 + kc]);
        }
        __syncthreads();
    }

    // stage 2: relu(T @ rho_w1 + b1) -> T
    {
        bf16x8 af[3];
#pragma unroll
        for (int kk = 0; kk < 3; ++kk) af[kk] = *(const bf16x8*)(&T[(w * 16 + lrow) * KP + kk * 32 + lk]);
#pragma unroll
        for (int nn = 0; nn < 6; ++nn) { acc[nn][0] = 0.f; acc[nn][1] = 0.f; acc[nn][2] = 0.f; acc[nn][3] = 0.f; }
#pragma unroll
        for (int nn = 0; nn < 6; ++nn)
#pragma unroll
            for (int kk = 0; kk < 3; ++kk)
                acc[nn] = __builtin_amdgcn_mfma_f32_16x16x32_bf16(
                    af[kk], *(const bf16x8*)(&WL[(nn * 16 + lrow) * KP + kk * 32 + lk]), acc[nn], 0, 0, 0);
        __syncthreads();
#pragma unroll
        for (int reg = 0; reg < 4; ++reg)
#pragma unroll
            for (int nn = 0; nn < 6; ++nn)
                T[(w * 16 + rsub + reg) * KP + nn * 16 + lrow] = f2bf(fmaxf(acc[nn][reg] + bc2[nn], 0.f));
        for (int i = t; i < 96 * 12; i += 256) {
            int n = i / 12, kc = (i - n * 12) * 8;
            *(uint4*)(&WL[n * KP + kc]) = *(const uint4*)(&w_rho2[n * 96 + kc]);
        }
        __syncthreads();
    }

    // stage 3: hb = bf16(hb + T @ rho_w2 + b2)
    {
        bf16x8 af[3];
#pragma unroll
        for (int kk = 0; kk < 3; ++kk) af[kk] = *(const bf16x8*)(&T[(w * 16 + lrow) * KP + kk * 32 + lk]);
#pragma unroll
        for (int nn = 0; nn < 6; ++nn) { acc[nn][0] = 0.f; acc[nn][1] = 0.f; acc[nn][2] = 0.f; acc[nn][3] = 0.f; }
#pragma unroll
        for (int nn = 0; nn < 6; ++nn)
#pragma unroll
            for (int kk = 0; kk < 3; ++kk)
                acc[nn] = __builtin_amdgcn_mfma_f32_16x16x32_bf16(
                    af[kk], *(const bf16x8*)(&WL[(nn * 16 + lrow) * KP + kk * 32 + lk]), acc[nn], 0, 0, 0);
#pragma unroll
        for (int reg = 0; reg < 4; ++reg) {
            int row = base + w * 16 + rsub + reg;
            if (row < N_NODES) {
#pragma unroll
                for (int nn = 0; nn < 6; ++nn) {
                    size_t idx = (size_t)row * 96 + nn * 16 + lrow;
                    float hv = bf2f(hb[idx]) + acc[nn][reg] + bc3[nn];
                    hb[idx] = f2bf(hv);
                }
            }
        }
    }
}

// ---------- GCN aggregation: row-per-16-lane-group (4 rows/wave) ----------
// xw' carries dinv[src]; agg = dv*(sum xw'[s] + xw'[row]); residual in bf16 hb.
// Each 16-lane group owns one row: no cross-group reduce, epilogue computed once,
// 8-deep gather unroll for MLP.  (Proven 271-µs configuration; VGPR 40.)

#define GA_EDGE(c) { uint3 gv = *(const uint3*)(&xw[(c) * 48 + f * 3]); \
    a[0] += bflo(gv.x); a[1] += bfhi(gv.x); \
    a[2] += bflo(gv.y); a[3] += bfhi(gv.y); \
    a[4] += bflo(gv.z); a[5] += bfhi(gv.z); }

__launch_bounds__(256)
__global__ void k_agg(const unsigned int* __restrict__ xw, const int* __restrict__ rowst,
                      const int* __restrict__ csr, const float* __restrict__ dinv,
                      const float* __restrict__ bias, const float* __restrict__ g,
                      const float* __restrict__ beta, ushort* __restrict__ hb) {
    const int lane = threadIdx.x & 63, wid = threadIdx.x >> 6;
    const int f = lane & 15;      // feature lane: features f*6..f*6+5
    const int eg = lane >> 4;     // row subgroup 0..3
    float bb[6], gg[6], be[6];
#pragma unroll
    for (int j = 0; j < 6; ++j) { bb[j] = bias[f * 6 + j]; gg[j] = g[f * 6 + j]; be[j] = beta[f * 6 + j]; }
    const int w = blockIdx.x * 4 + wid, stride = gridDim.x * 4;
    for (int base = w * 4; base < N_NODES; base += stride * 4) {
        const int row = base + eg;   // N_NODES % 4 == 0 -> always valid
        int rs = rowst[row], re = rowst[row + 1];
        float dv = dinv[row];
        uint3 sv = *(const uint3*)(&xw[row * 48 + f * 3]);
        float a[6];
        a[0] = bflo(sv.x); a[1] = bfhi(sv.x);
        a[2] = bflo(sv.y); a[3] = bfhi(sv.y);
        a[4] = bflo(sv.z); a[5] = bfhi(sv.z);
        int i = rs;
        for (; i + 7 < re; i += 8) {
            int c0 = csr[i], c1 = csr[i + 1], c2 = csr[i + 2], c3 = csr[i + 3];
            int c4 = csr[i + 4], c5 = csr[i + 5], c6 = csr[i + 6], c7 = csr[i + 7];
            GA_EDGE(c0); GA_EDGE(c1); GA_EDGE(c2); GA_EDGE(c3);
            GA_EDGE(c4); GA_EDGE(c5); GA_EDGE(c6); GA_EDGE(c7);
        }
        for (; i + 3 < re; i += 4) {
            int c0 = csr[i], c1 = csr[i + 1], c2 = csr[i + 2], c3 = csr[i + 3];
            GA_EDGE(c0); GA_EDGE(c1); GA_EDGE(c2); GA_EDGE(c3);
        }
        for (; i < re; ++i) {
            int c0 = csr[i];
            GA_EDGE(c0);
        }
        // epilogue (per 16-lane group; LN reduce within group)
        float s = 0.f, s2 = 0.f;
#pragma unroll
        for (int j = 0; j < 6; ++j) {
            a[j] = fmaf(a[j], dv, bb[j]);
            a[j] = gelu_f(a[j]);
            s += a[j]; s2 += a[j] * a[j];
        }
#pragma unroll
        for (int off = 1; off < 16; off <<= 1) { s += __shfl_xor(s, off); s2 += __shfl_xor(s2, off); }
        float mean = s * (1.f / 96.f);
        float var = s2 * (1.f / 96.f) - mean * mean;
        float rs_ = rsqrtf(var + LN_EPS_F);
        unsigned int* hbp = (unsigned int*)(hb + (size_t)row * 96 + f * 6);
        unsigned hv0 = hbp[0], hv1 = hbp[1], hv2 = hbp[2];
        float v0 = bflo(hv0) + (a[0] - mean) * rs_ * gg[0] + be[0];
        float v1 = bfhi(hv0) + (a[1] - mean) * rs_ * gg[1] + be[1];
        float v2 = bflo(hv1) + (a[2] - mean) * rs_ * gg[2] + be[2];
        float v3 = bfhi(hv1) + (a[3] - mean) * rs_ * gg[3] + be[3];
        float v4 = bflo(hv2) + (a[4] - mean) * rs_ * gg[4] + be[4];
        float v5 = bfhi(hv2) + (a[5] - mean) * rs_ * gg[5] + be[5];
        hbp[0] = (unsigned)f2bf(v0) | ((unsigned)f2bf(v1) << 16);
        hbp[1] = (unsigned)f2bf(v2) | ((unsigned)f2bf(v3) << 16);
        hbp[2] = (unsigned)f2bf(v4) | ((unsigned)f2bf(v5) << 16);
    }
}

// ---------- host ----------

extern "C" void kernel_launch(void* const* d_in, const int* in_sizes, int n_in,
                              void* d_out, int out_size, void* d_ws, size_t ws_size,
                              hipStream_t stream) {
    (void)in_sizes; (void)n_in; (void)out_size; (void)ws_size;
    const float* x       = (const float*)d_in[0];
    const int*   eidx    = (const int*)d_in[1];
    const float* eigvecs = (const float*)d_in[2];
    const float* eigvals = (const float*)d_in[3];
    const float* enc_W   = (const float*)d_in[4];
    const float* enc_b   = (const float*)d_in[5];
    const float* in_g    = (const float*)d_in[6];
    const float* in_b    = (const float*)d_in[7];
    const float* phi_w1  = (const float*)d_in[8];
    const float* phi_w2  = (const float*)d_in[9];
    const float* rho_w1  = (const float*)d_in[10];
    const float* rho_b1  = (const float*)d_in[11];
    const float* rho_w2  = (const float*)d_in[12];
    const float* rho_b2  = (const float*)d_in[13];
    const float* pe_eps  = (const float*)d_in[14];
    const float* conv_W  = (const float*)d_in[15];
    const float* conv_b  = (const float*)d_in[16];
    const float* norm_g  = (const float*)d_in[17];
    const float* norm_b  = (const float*)d_in[18];
    const float* head_w1 = (const float*)d_in[19];
    const float* head_b1 = (const float*)d_in[20];
    const float* head_g  = (const float*)d_in[21];
    const float* head_b  = (const float*)d_in[22];
    const float* head_w2 = (const float*)d_in[23];
    const float* head_b2 = (const float*)d_in[24];
    float* out = (float*)d_out;

    const int* src = eidx;
    const int* dst = eidx + N_EDGES;

    char* ws = (char*)d_ws;
    size_t off = 0;
    auto alloc = [&](size_t bytes) {
        void* p = ws + off;
        off += (bytes + 255) & ~(size_t)255;
        return p;
    };
    ushort*   hb    = (ushort*)alloc(sizeof(ushort) * (size_t)N_NODES * H_DIM);
    ushort*   bufA  = (ushort*)alloc(sizeof(ushort) * (size_t)N_NODES * H_DIM);
    ushort*   wbf   = (ushort*)alloc(sizeof(ushort) * (12288 + 8 * 9216 + 1536));
    int*      rowst = (int*)alloc(sizeof(int) * (N_NODES + 1));
    float*    dinv  = (float*)alloc(sizeof(float) * N_NODES);
    int*      csr   = (int*)alloc(sizeof(int) * N_EDGES);
    int*      cm    = (int*)alloc(sizeof(int) * (NBK * NPB + 1));
    unsigned* eb    = (unsigned*)bufA;  // alias: eb (3.2MB) dead before GEMMs use bufA

    const int gb = (N_NODES / 16 + 3) / 4;         // 782 blocks, wave-per-16-row-group
    const int pb = (N_NODES + 63) / 64;            // 782
    const int prep_n = 12288 + 8 * 9216 + 1536;

    WSrc wsrc;
    wsrc.p[0] = enc_W; wsrc.p[1] = phi_w2; wsrc.p[2] = rho_w1; wsrc.p[3] = rho_w2;
    for (int l = 0; l < 4; ++l) wsrc.p[4 + l] = conv_W + (size_t)l * 9216;
    wsrc.p[8] = head_w1; wsrc.p[9] = head_w2;
    k_prep<<<(prep_n + 255) / 256, 256, 0, stream>>>(wsrc, wbf);

    // bucketed CSR build (packed 4B eb)
    k_binA<<<NPB, 256, 0, stream>>>(dst, cm);
    k_binB<<<1, 1024, 0, stream>>>(cm, NBK * NPB);
    k_binC<<<NPB, 256, 0, stream>>>(src, dst, cm, eb);
    k_binD<<<NBK, 1024, 0, stream>>>(eb, cm, rowst, dinv, csr);

    const ushort* w_enc  = wbf;
    const ushort* w_head = wbf + 12288 + 7 * 9216;
    const ushort* w_2t   = wbf + 12288 + 8 * 9216;

    // encoder: hb = bf16(LN(x @ enc_W + enc_b))
    k_gemm<IN_DIM, float, 2><<<gb, 256, 0, stream>>>(x, w_enc, enc_b, in_g, in_b,
                                                     nullptr, nullptr, nullptr, hb);

    // fused PE chain: hb += PE
    k_pe<<<pb, 256, 0, stream>>>(eigvecs, eigvals, pe_eps, phi_w1,
                                 wbf + 12288, wbf + 12288 + 9216, wbf + 12288 + 2 * 9216,
                                 rho_b1, rho_b2, hb);

    // GCN layers: xw' = (hb @ conv_W) * dinv[row]; pull agg + epilogue, bf16 residual
    for (int l = 0; l < L_LAYERS; ++l) {
        k_gemm<96, ushort, 0><<<gb, 256, 0, stream>>>(hb, wbf + 12288 + (size_t)(3 + l) * 9216,
                                                      nullptr, nullptr, nullptr, dinv,
                                                      nullptr, nullptr, bufA);
        k_agg<<<2048, 256, 0, stream>>>((const unsigned int*)bufA, rowst, csr, dinv,
                                        conv_b + (size_t)l * 96, norm_g + (size_t)l * 96,
                                        norm_b + (size_t)l * 96, hb);
    }

    // fused head: out = LN(gelu(hb@w1+b1)) @ w2 + b2 (second MFMA)
    k_gemm<96, ushort, 5><<<gb, 256, 0, stream>>>(hb, w_head, head_b1, head_g, head_b,
                                                  nullptr, w_2t, head_b2, out);
}